// Round 12
// baseline (183.736 us; speedup 1.0000x reference)
//
#include <hip/hip_runtime.h>
#include <math.h>

#define TWO_H 4096
#define HALF_H 2048
#define NGROUPS 8
#define BLOCK 256
#define WPB 4      // waves per block
#define RPW 4      // consecutive rows per wave
#define GRID 2048  // 8192 waves x 4 rows = 32768 rows

typedef int    vi4 __attribute__((ext_vector_type(4)));
typedef float  vf4 __attribute__((ext_vector_type(4)));
typedef __fp16 vh2 __attribute__((ext_vector_type(2)));

// R10's exact spill-free body (f16-packed row buffer, 8x4-elem chunks, no
// LDS, no barriers), but each wave owns 4 CONSECUTIVE rows: wscale row +
// bias stay L1-resident and are reused 4x; x-stream is one contiguous 64KB
// burst per wave; out is a contiguous 32KB burst.
__global__ __launch_bounds__(BLOCK, 4) void swiglu_requant_kernel(
    const int* __restrict__ x,         // [N, 4096] int32
    const float* __restrict__ wscale,  // [G, 4096]
    const float* __restrict__ ascale,  // [N]
    const float* __restrict__ bias,    // [4096]
    const float* __restrict__ qscale,  // [G]
    const int* __restrict__ gindex,    // [G]
    int* __restrict__ out,             // [N, 2048] int32 (int8 values widened)
    int n_rows)
{
    const int lane = threadIdx.x & 63;
    const int wid  = blockIdx.x * WPB + (threadIdx.x >> 6);

    const int r0 = wid * RPW;
    if (r0 >= n_rows) return;
    int rend = r0 + RPW; if (rend > n_rows) rend = n_rows;

    // group boundaries (cumsum), wave-uniform
    int cum[NGROUPS];
    {
        int c = 0;
#pragma unroll
        for (int g = 0; g < NGROUPS; ++g) { c += gindex[g]; cum[g] = c; }
    }

    for (int row = r0; row < rend; ++row) {
        int gid = 0;
#pragma unroll
        for (int g = 0; g < NGROUPS; ++g) gid += (row >= cum[g]) ? 1 : 0;

        const float a_s = ascale[row];
        const float q_s = qscale[gid];

        const int*   xrow = x + (long)row * TWO_H;
        const float* wrow = wscale + (long)gid * TWO_H;

        vh2   o16[16];            // packed row buffer: 16 VGPR
        float lmax = 0.0f;

#pragma unroll
        for (int c = 0; c < 8; ++c) {
            const int cg = c * 256 + lane * 4;   // gate col start (4 elems)

            vi4 g = *(const vi4*)(xrow + cg);
            vi4 u = *(const vi4*)(xrow + HALF_H + cg);
            vf4 wg = *(const vf4*)(wrow + cg);
            vf4 wu = *(const vf4*)(wrow + HALF_H + cg);
            vf4 bg = *(const vf4*)(bias + cg);
            vf4 bu = *(const vf4*)(bias + HALF_H + cg);

            float gi[4] = {(float)g.x, (float)g.y, (float)g.z, (float)g.w};
            float ui[4] = {(float)u.x, (float)u.y, (float)u.z, (float)u.w};
            float wgx[4] = {wg.x, wg.y, wg.z, wg.w};
            float wux[4] = {wu.x, wu.y, wu.z, wu.w};
            float bgx[4] = {bg.x, bg.y, bg.z, bg.w};
            float bux[4] = {bu.x, bu.y, bu.z, bu.w};

            float ov[4];
#pragma unroll
            for (int i = 0; i < 4; ++i) {
                float gv = (gi[i] + bgx[i]) * wgx[i] * a_s;
                float uv = (ui[i] + bux[i]) * wux[i] * a_s;
                float e  = __expf(-uv);
                float sv = uv * __builtin_amdgcn_rcpf(1.0f + e);  // silu(up)
                float o  = sv * gv * q_s;
                ov[i] = o;
                lmax = fmaxf(lmax, fabsf(o));
            }
            // pack to f16 pairs (v_cvt_pkrtz_f16_f32)
            o16[c * 2]     = __builtin_amdgcn_cvt_pkrtz(ov[0], ov[1]);
            o16[c * 2 + 1] = __builtin_amdgcn_cvt_pkrtz(ov[2], ov[3]);
        }

        // 64-lane max reduce, registers only (lmax is exact f32)
#pragma unroll
        for (int m = 1; m < 64; m <<= 1)
            lmax = fmaxf(lmax, __shfl_xor(lmax, m, 64));

        const float scale = 127.0f / lmax;

        int* orow = out + (long)row * HALF_H;
#pragma unroll
        for (int c = 0; c < 8; ++c) {
            const int co = c * 256 + lane * 4;
            float ov[4] = {(float)o16[c * 2].x,     (float)o16[c * 2].y,
                           (float)o16[c * 2 + 1].x, (float)o16[c * 2 + 1].y};
            int w[4];
#pragma unroll
            for (int i = 0; i < 4; ++i) {
                float v = ov[i] * scale;
                v = fminf(fmaxf(v, -128.0f), 127.0f);  // clip then round (matches ref)
                w[i] = (int)rintf(v);                   // round half-to-even
            }
            vi4 wv = {w[0], w[1], w[2], w[3]};
            *(vi4*)(orow + co) = wv;
        }
    }
}

extern "C" void kernel_launch(void* const* d_in, const int* in_sizes, int n_in,
                              void* d_out, int out_size, void* d_ws, size_t ws_size,
                              hipStream_t stream) {
    const int*   x      = (const int*)d_in[0];
    const float* wscale = (const float*)d_in[1];
    const float* ascale = (const float*)d_in[2];
    const float* bias   = (const float*)d_in[3];
    const float* qscale = (const float*)d_in[4];
    const int*   gindex = (const int*)d_in[5];
    int* out = (int*)d_out;

    const int n_rows = in_sizes[0] / TWO_H;  // 32768
    const int grid = (n_rows + WPB * RPW - 1) / (WPB * RPW);  // 2048

    swiglu_requant_kernel<<<grid, BLOCK, 0, stream>>>(
        x, wscale, ascale, bias, qscale, gindex, out, n_rows);
}

// Round 13
// 182.684 us; speedup vs baseline: 1.0058x; 1.0058x over previous
//
#include <hip/hip_runtime.h>
#include <math.h>

#define TWO_H 4096
#define HALF_H 2048
#define NGROUPS 8
#define BLOCK 256
#define WPB 4      // waves per block
#define GRID 2048  // 8192 waves; grid-stride interleaved (R10's proven mapping)

typedef int    vi4 __attribute__((ext_vector_type(4)));
typedef float  vf4 __attribute__((ext_vector_type(4)));
typedef __fp16 vh2 __attribute__((ext_vector_type(2)));
typedef __fp16 vh4 __attribute__((ext_vector_type(4)));
typedef __fp16 vh8 __attribute__((ext_vector_type(8)));

// ---------- table build: per gate-col {wg*q, b*wg*q, wu, b*wu} as 4x f16 ----------
__global__ __launch_bounds__(BLOCK) void build_tables_kernel(
    const float* __restrict__ wscale, const float* __restrict__ bias,
    const float* __restrict__ qscale, __fp16* __restrict__ tbl)
{
    const int idx = blockIdx.x * BLOCK + threadIdx.x;   // [0, G*2048)
    if (idx >= NGROUPS * HALF_H) return;
    const int g = idx >> 11;
    const int c = idx & (HALF_H - 1);
    const float q  = qscale[g];
    const float wg = wscale[(long)g * TWO_H + c];
    const float wu = wscale[(long)g * TWO_H + HALF_H + c];
    const float bg = bias[c];
    const float bu = bias[HALF_H + c];
    vh4 v = {(__fp16)(wg * q), (__fp16)(bg * wg * q),
             (__fp16)wu,       (__fp16)(bu * wu)};
    *(vh4*)(tbl + (long)idx * 4) = v;
}

// ---------- main: R10 structure, operand loads via packed f16 table ----------
__global__ __launch_bounds__(BLOCK, 4) void swiglu_requant_tbl_kernel(
    const int* __restrict__ x,        // [N, 4096] int32
    const __fp16* __restrict__ tbl,   // [G, 2048, 4] f16
    const float* __restrict__ ascale, // [N]
    const int* __restrict__ gindex,   // [G]
    int* __restrict__ out,            // [N, 2048] int32
    int n_rows)
{
    const int lane   = threadIdx.x & 63;
    const int wid    = blockIdx.x * WPB + (threadIdx.x >> 6);
    const int nwaves = GRID * WPB;

    int cum[NGROUPS];
    {
        int c = 0;
#pragma unroll
        for (int g = 0; g < NGROUPS; ++g) { c += gindex[g]; cum[g] = c; }
    }

    for (int row = wid; row < n_rows; row += nwaves) {
        int gid = 0;
#pragma unroll
        for (int g = 0; g < NGROUPS; ++g) gid += (row >= cum[g]) ? 1 : 0;

        const float a_s = ascale[row];
        const int*    xrow = x + (long)row * TWO_H;
        const __fp16* trow = tbl + (long)gid * HALF_H * 4;

        vh2   o16[16];
        float lmax = 0.0f;

#pragma unroll
        for (int c = 0; c < 8; ++c) {
            const int cg = c * 256 + lane * 4;   // gate col start (4 cols)

            vi4 g = *(const vi4*)(xrow + cg);
            vi4 u = *(const vi4*)(xrow + HALF_H + cg);
            vh8 t0 = *(const vh8*)(trow + (long)cg * 4);      // cols cg, cg+1
            vh8 t1 = *(const vh8*)(trow + (long)cg * 4 + 8);  // cols cg+2, cg+3

            float gi[4] = {(float)g.x, (float)g.y, (float)g.z, (float)g.w};
            float ui[4] = {(float)u.x, (float)u.y, (float)u.z, (float)u.w};
            float wgq[4]  = {(float)t0[0], (float)t0[4], (float)t1[0], (float)t1[4]};
            float bwgq[4] = {(float)t0[1], (float)t0[5], (float)t1[1], (float)t1[5]};
            float wux[4]  = {(float)t0[2], (float)t0[6], (float)t1[2], (float)t1[6]};
            float bwux[4] = {(float)t0[3], (float)t0[7], (float)t1[3], (float)t1[7]};

            float ov[4];
#pragma unroll
            for (int i = 0; i < 4; ++i) {
                float gvq = fmaf(gi[i], wgq[i], bwgq[i]) * a_s;   // gate * q folded
                float uv  = fmaf(ui[i], wux[i], bwux[i]) * a_s;
                float e   = __expf(-uv);
                float sv  = uv * __builtin_amdgcn_rcpf(1.0f + e); // silu(up)
                float o   = sv * gvq;
                ov[i] = o;
                lmax = fmaxf(lmax, fabsf(o));
            }
            o16[c * 2]     = __builtin_amdgcn_cvt_pkrtz(ov[0], ov[1]);
            o16[c * 2 + 1] = __builtin_amdgcn_cvt_pkrtz(ov[2], ov[3]);
        }

#pragma unroll
        for (int m = 1; m < 64; m <<= 1)
            lmax = fmaxf(lmax, __shfl_xor(lmax, m, 64));

        const float scale = 127.0f / lmax;

        int* orow = out + (long)row * HALF_H;
#pragma unroll
        for (int c = 0; c < 8; ++c) {
            const int co = c * 256 + lane * 4;
            float ov[4] = {(float)o16[c * 2].x,     (float)o16[c * 2].y,
                           (float)o16[c * 2 + 1].x, (float)o16[c * 2 + 1].y};
            int w[4];
#pragma unroll
            for (int i = 0; i < 4; ++i) {
                float v = ov[i] * scale;
                v = fminf(fmaxf(v, -128.0f), 127.0f);
                w[i] = (int)rintf(v);
            }
            vi4 wv = {w[0], w[1], w[2], w[3]};
            *(vi4*)(orow + co) = wv;
        }
    }
}

// ---------- fallback (R10 verbatim) if ws is too small ----------
__global__ __launch_bounds__(BLOCK, 4) void swiglu_requant_kernel(
    const int* __restrict__ x, const float* __restrict__ wscale,
    const float* __restrict__ ascale, const float* __restrict__ bias,
    const float* __restrict__ qscale, const int* __restrict__ gindex,
    int* __restrict__ out, int n_rows)
{
    const int lane   = threadIdx.x & 63;
    const int wid    = blockIdx.x * WPB + (threadIdx.x >> 6);
    const int nwaves = GRID * WPB;
    int cum[NGROUPS];
    {
        int c = 0;
#pragma unroll
        for (int g = 0; g < NGROUPS; ++g) { c += gindex[g]; cum[g] = c; }
    }
    for (int row = wid; row < n_rows; row += nwaves) {
        int gid = 0;
#pragma unroll
        for (int g = 0; g < NGROUPS; ++g) gid += (row >= cum[g]) ? 1 : 0;
        const float a_s = ascale[row];
        const float q_s = qscale[gid];
        const int*   xrow = x + (long)row * TWO_H;
        const float* wrow = wscale + (long)gid * TWO_H;
        vh2   o16[16];
        float lmax = 0.0f;
#pragma unroll
        for (int c = 0; c < 8; ++c) {
            const int cg = c * 256 + lane * 4;
            vi4 g = *(const vi4*)(xrow + cg);
            vi4 u = *(const vi4*)(xrow + HALF_H + cg);
            vf4 wg = *(const vf4*)(wrow + cg);
            vf4 wu = *(const vf4*)(wrow + HALF_H + cg);
            vf4 bg = *(const vf4*)(bias + cg);
            vf4 bu = *(const vf4*)(bias + HALF_H + cg);
            float gi[4] = {(float)g.x, (float)g.y, (float)g.z, (float)g.w};
            float ui[4] = {(float)u.x, (float)u.y, (float)u.z, (float)u.w};
            float wgx[4] = {wg.x, wg.y, wg.z, wg.w};
            float wux[4] = {wu.x, wu.y, wu.z, wu.w};
            float bgx[4] = {bg.x, bg.y, bg.z, bg.w};
            float bux[4] = {bu.x, bu.y, bu.z, bu.w};
            float ov[4];
#pragma unroll
            for (int i = 0; i < 4; ++i) {
                float gv = (gi[i] + bgx[i]) * wgx[i] * a_s;
                float uv = (ui[i] + bux[i]) * wux[i] * a_s;
                float e  = __expf(-uv);
                float sv = uv * __builtin_amdgcn_rcpf(1.0f + e);
                float o  = sv * gv * q_s;
                ov[i] = o;
                lmax = fmaxf(lmax, fabsf(o));
            }
            o16[c * 2]     = __builtin_amdgcn_cvt_pkrtz(ov[0], ov[1]);
            o16[c * 2 + 1] = __builtin_amdgcn_cvt_pkrtz(ov[2], ov[3]);
        }
#pragma unroll
        for (int m = 1; m < 64; m <<= 1)
            lmax = fmaxf(lmax, __shfl_xor(lmax, m, 64));
        const float scale = 127.0f / lmax;
        int* orow = out + (long)row * HALF_H;
#pragma unroll
        for (int c = 0; c < 8; ++c) {
            const int co = c * 256 + lane * 4;
            float ov[4] = {(float)o16[c * 2].x,     (float)o16[c * 2].y,
                           (float)o16[c * 2 + 1].x, (float)o16[c * 2 + 1].y};
            int w[4];
#pragma unroll
            for (int i = 0; i < 4; ++i) {
                float v = ov[i] * scale;
                v = fminf(fmaxf(v, -128.0f), 127.0f);
                w[i] = (int)rintf(v);
            }
            vi4 wv = {w[0], w[1], w[2], w[3]};
            *(vi4*)(orow + co) = wv;
        }
    }
}

extern "C" void kernel_launch(void* const* d_in, const int* in_sizes, int n_in,
                              void* d_out, int out_size, void* d_ws, size_t ws_size,
                              hipStream_t stream) {
    const int*   x      = (const int*)d_in[0];
    const float* wscale = (const float*)d_in[1];
    const float* ascale = (const float*)d_in[2];
    const float* bias   = (const float*)d_in[3];
    const float* qscale = (const float*)d_in[4];
    const int*   gindex = (const int*)d_in[5];
    int* out = (int*)d_out;

    const int n_rows = in_sizes[0] / TWO_H;  // 32768
    const size_t need = (size_t)NGROUPS * HALF_H * 4 * sizeof(__fp16);  // 128 KiB

    if (ws_size >= need) {
        __fp16* tbl = (__fp16*)d_ws;
        const int nt = NGROUPS * HALF_H;
        build_tables_kernel<<<(nt + BLOCK - 1) / BLOCK, BLOCK, 0, stream>>>(
            wscale, bias, qscale, tbl);
        swiglu_requant_tbl_kernel<<<GRID, BLOCK, 0, stream>>>(
            x, tbl, ascale, gindex, out, n_rows);
    } else {
        swiglu_requant_kernel<<<GRID, BLOCK, 0, stream>>>(
            x, wscale, ascale, bias, qscale, gindex, out, n_rows);
    }
}

// Round 14
// 161.965 us; speedup vs baseline: 1.1344x; 1.1279x over previous
//
#include <hip/hip_runtime.h>
#include <math.h>

#define TWO_H 4096
#define HALF_H 2048
#define NGROUPS 8
#define BLOCK 256
#define WPB 4      // waves per block
#define GRID 2048  // 8192 waves; grid-stride interleaved (proven best mapping)

typedef int    vi4 __attribute__((ext_vector_type(4)));
typedef float  vf4 __attribute__((ext_vector_type(4)));
typedef __fp16 vh2 __attribute__((ext_vector_type(2)));

// R10's exact body (167 us baseline); ONLY change: output stores are
// non-temporal (bypass L2 write-allocate so the 256MB write stream stops
// competing with the 512MB read stream for L2 capacity).
__global__ __launch_bounds__(BLOCK, 4) void swiglu_requant_kernel(
    const int* __restrict__ x,         // [N, 4096] int32
    const float* __restrict__ wscale,  // [G, 4096]
    const float* __restrict__ ascale,  // [N]
    const float* __restrict__ bias,    // [4096]
    const float* __restrict__ qscale,  // [G]
    const int* __restrict__ gindex,    // [G]
    int* __restrict__ out,             // [N, 2048] int32 (int8 values widened)
    int n_rows)
{
    const int lane   = threadIdx.x & 63;
    const int wid    = blockIdx.x * WPB + (threadIdx.x >> 6);
    const int nwaves = GRID * WPB;

    // group boundaries (cumsum), wave-uniform
    int cum[NGROUPS];
    {
        int c = 0;
#pragma unroll
        for (int g = 0; g < NGROUPS; ++g) { c += gindex[g]; cum[g] = c; }
    }

    for (int row = wid; row < n_rows; row += nwaves) {
        int gid = 0;
#pragma unroll
        for (int g = 0; g < NGROUPS; ++g) gid += (row >= cum[g]) ? 1 : 0;

        const float a_s = ascale[row];
        const float q_s = qscale[gid];

        const int*   xrow = x + (long)row * TWO_H;
        const float* wrow = wscale + (long)gid * TWO_H;

        vh2   o16[16];            // packed row buffer: 16 VGPR
        float lmax = 0.0f;

#pragma unroll
        for (int c = 0; c < 8; ++c) {
            const int cg = c * 256 + lane * 4;   // gate col start (4 elems)

            vi4 g = *(const vi4*)(xrow + cg);
            vi4 u = *(const vi4*)(xrow + HALF_H + cg);
            vf4 wg = *(const vf4*)(wrow + cg);
            vf4 wu = *(const vf4*)(wrow + HALF_H + cg);
            vf4 bg = *(const vf4*)(bias + cg);
            vf4 bu = *(const vf4*)(bias + HALF_H + cg);

            float gi[4] = {(float)g.x, (float)g.y, (float)g.z, (float)g.w};
            float ui[4] = {(float)u.x, (float)u.y, (float)u.z, (float)u.w};
            float wgx[4] = {wg.x, wg.y, wg.z, wg.w};
            float wux[4] = {wu.x, wu.y, wu.z, wu.w};
            float bgx[4] = {bg.x, bg.y, bg.z, bg.w};
            float bux[4] = {bu.x, bu.y, bu.z, bu.w};

            float ov[4];
#pragma unroll
            for (int i = 0; i < 4; ++i) {
                float gv = (gi[i] + bgx[i]) * wgx[i] * a_s;
                float uv = (ui[i] + bux[i]) * wux[i] * a_s;
                float e  = __expf(-uv);
                float sv = uv * __builtin_amdgcn_rcpf(1.0f + e);  // silu(up)
                float o  = sv * gv * q_s;
                ov[i] = o;
                lmax = fmaxf(lmax, fabsf(o));
            }
            o16[c * 2]     = __builtin_amdgcn_cvt_pkrtz(ov[0], ov[1]);
            o16[c * 2 + 1] = __builtin_amdgcn_cvt_pkrtz(ov[2], ov[3]);
        }

        // 64-lane max reduce, registers only (lmax is exact f32)
#pragma unroll
        for (int m = 1; m < 64; m <<= 1)
            lmax = fmaxf(lmax, __shfl_xor(lmax, m, 64));

        const float scale = 127.0f / lmax;

        int* orow = out + (long)row * HALF_H;
#pragma unroll
        for (int c = 0; c < 8; ++c) {
            const int co = c * 256 + lane * 4;
            float ov[4] = {(float)o16[c * 2].x,     (float)o16[c * 2].y,
                           (float)o16[c * 2 + 1].x, (float)o16[c * 2 + 1].y};
            int w[4];
#pragma unroll
            for (int i = 0; i < 4; ++i) {
                float v = ov[i] * scale;
                v = fminf(fmaxf(v, -128.0f), 127.0f);  // clip then round (matches ref)
                w[i] = (int)rintf(v);                   // round half-to-even
            }
            vi4 wv = {w[0], w[1], w[2], w[3]};
            __builtin_nontemporal_store(wv, (vi4*)(orow + co));  // nt STORE only
        }
    }
}

extern "C" void kernel_launch(void* const* d_in, const int* in_sizes, int n_in,
                              void* d_out, int out_size, void* d_ws, size_t ws_size,
                              hipStream_t stream) {
    const int*   x      = (const int*)d_in[0];
    const float* wscale = (const float*)d_in[1];
    const float* ascale = (const float*)d_in[2];
    const float* bias   = (const float*)d_in[3];
    const float* qscale = (const float*)d_in[4];
    const int*   gindex = (const int*)d_in[5];
    int* out = (int*)d_out;

    const int n_rows = in_sizes[0] / TWO_H;  // 32768

    swiglu_requant_kernel<<<GRID, BLOCK, 0, stream>>>(
        x, wscale, ascale, bias, qscale, gindex, out, n_rows);
}

// Round 15
// 154.332 us; speedup vs baseline: 1.1905x; 1.0495x over previous
//
#include <hip/hip_runtime.h>
#include <math.h>

#define TWO_H 4096
#define HALF_H 2048
#define NGROUPS 8
#define BLOCK 256
#define WPB 4      // waves per block
#define GRID 2048  // 8192 waves; grid-stride interleaved (proven best mapping)

typedef int    vi4 __attribute__((ext_vector_type(4)));
typedef float  vf4 __attribute__((ext_vector_type(4)));
typedef __fp16 vh2 __attribute__((ext_vector_type(2)));

// R14 body (nt-store, f16-packed row buffer) + cross-row software pipeline:
// next row's first 2 chunks of x (+ its ascale) are prefetched BEFORE the
// reduce/store epilogue, keeping HBM reads in flight across the per-row
// serial tail (shuffle-reduce + stores).
__global__ __launch_bounds__(BLOCK, 4) void swiglu_requant_kernel(
    const int* __restrict__ x,         // [N, 4096] int32
    const float* __restrict__ wscale,  // [G, 4096]
    const float* __restrict__ ascale,  // [N]
    const float* __restrict__ bias,    // [4096]
    const float* __restrict__ qscale,  // [G]
    const int* __restrict__ gindex,    // [G]
    int* __restrict__ out,             // [N, 2048] int32 (int8 values widened)
    int n_rows)
{
    const int lane   = threadIdx.x & 63;
    const int wid    = blockIdx.x * WPB + (threadIdx.x >> 6);
    const int nwaves = GRID * WPB;

    // group boundaries (cumsum), wave-uniform
    int cum[NGROUPS];
    {
        int c = 0;
#pragma unroll
        for (int g = 0; g < NGROUPS; ++g) { c += gindex[g]; cum[g] = c; }
    }

    int row = wid;
    if (row >= n_rows) return;

    const int lofs = lane * 4;

    // prime the pipeline: row's chunks 0,1 + ascale
    const int* xrow = x + (long)row * TWO_H;
    vi4 pg[2], pu[2];
    pg[0] = *(const vi4*)(xrow + lofs);
    pu[0] = *(const vi4*)(xrow + HALF_H + lofs);
    pg[1] = *(const vi4*)(xrow + 256 + lofs);
    pu[1] = *(const vi4*)(xrow + HALF_H + 256 + lofs);
    float pa = ascale[row];

    while (true) {
        int gid = 0;
#pragma unroll
        for (int g = 0; g < NGROUPS; ++g) gid += (row >= cum[g]) ? 1 : 0;

        const float a_s = pa;
        const float q_s = qscale[gid];
        const float* wrow = wscale + (long)gid * TWO_H;

        vh2   o16[16];
        float lmax = 0.0f;

        auto do_chunk = [&](int c, vi4 g, vi4 u) {
            const int cg = c * 256 + lofs;
            vf4 wg = *(const vf4*)(wrow + cg);
            vf4 wu = *(const vf4*)(wrow + HALF_H + cg);
            vf4 bg = *(const vf4*)(bias + cg);
            vf4 bu = *(const vf4*)(bias + HALF_H + cg);

            float gi[4] = {(float)g.x, (float)g.y, (float)g.z, (float)g.w};
            float ui[4] = {(float)u.x, (float)u.y, (float)u.z, (float)u.w};
            float wgx[4] = {wg.x, wg.y, wg.z, wg.w};
            float wux[4] = {wu.x, wu.y, wu.z, wu.w};
            float bgx[4] = {bg.x, bg.y, bg.z, bg.w};
            float bux[4] = {bu.x, bu.y, bu.z, bu.w};

            float ov[4];
#pragma unroll
            for (int i = 0; i < 4; ++i) {
                float gv = (gi[i] + bgx[i]) * wgx[i] * a_s;
                float uv = (ui[i] + bux[i]) * wux[i] * a_s;
                float e  = __expf(-uv);
                float sv = uv * __builtin_amdgcn_rcpf(1.0f + e);  // silu(up)
                float o  = sv * gv * q_s;
                ov[i] = o;
                lmax = fmaxf(lmax, fabsf(o));
            }
            o16[c * 2]     = __builtin_amdgcn_cvt_pkrtz(ov[0], ov[1]);
            o16[c * 2 + 1] = __builtin_amdgcn_cvt_pkrtz(ov[2], ov[3]);
        };

        // chunks 0,1 from prefetched registers
        do_chunk(0, pg[0], pu[0]);
        do_chunk(1, pg[1], pu[1]);
        // chunks 2..7: load + compute
#pragma unroll
        for (int c = 2; c < 8; ++c) {
            const int cg = c * 256 + lofs;
            vi4 g = *(const vi4*)(xrow + cg);
            vi4 u = *(const vi4*)(xrow + HALF_H + cg);
            do_chunk(c, g, u);
        }

        // ---- prefetch next row's chunks 0,1 + ascale (in flight across epilogue)
        const int  nrow = row + nwaves;
        const bool hn   = (nrow < n_rows);
        const int* nx   = x + (long)(hn ? nrow : wid) * TWO_H;  // safe dummy addr
        pg[0] = *(const vi4*)(nx + lofs);
        pu[0] = *(const vi4*)(nx + HALF_H + lofs);
        pg[1] = *(const vi4*)(nx + 256 + lofs);
        pu[1] = *(const vi4*)(nx + HALF_H + 256 + lofs);
        pa    = ascale[hn ? nrow : wid];

        // ---- epilogue: reduce, scale, nt-stores
#pragma unroll
        for (int m = 1; m < 64; m <<= 1)
            lmax = fmaxf(lmax, __shfl_xor(lmax, m, 64));

        const float scale = 127.0f / lmax;

        int* orow = out + (long)row * HALF_H;
#pragma unroll
        for (int c = 0; c < 8; ++c) {
            const int co = c * 256 + lofs;
            float ov[4] = {(float)o16[c * 2].x,     (float)o16[c * 2].y,
                           (float)o16[c * 2 + 1].x, (float)o16[c * 2 + 1].y};
            int w[4];
#pragma unroll
            for (int i = 0; i < 4; ++i) {
                float v = ov[i] * scale;
                v = fminf(fmaxf(v, -128.0f), 127.0f);  // clip then round (matches ref)
                w[i] = (int)rintf(v);                   // round half-to-even
            }
            vi4 wv = {w[0], w[1], w[2], w[3]};
            __builtin_nontemporal_store(wv, (vi4*)(orow + co));
        }

        if (!hn) break;
        row  = nrow;
        xrow = nx;
    }
}

extern "C" void kernel_launch(void* const* d_in, const int* in_sizes, int n_in,
                              void* d_out, int out_size, void* d_ws, size_t ws_size,
                              hipStream_t stream) {
    const int*   x      = (const int*)d_in[0];
    const float* wscale = (const float*)d_in[1];
    const float* ascale = (const float*)d_in[2];
    const float* bias   = (const float*)d_in[3];
    const float* qscale = (const float*)d_in[4];
    const int*   gindex = (const int*)d_in[5];
    int* out = (int*)d_out;

    const int n_rows = in_sizes[0] / TWO_H;  // 32768

    swiglu_requant_kernel<<<GRID, BLOCK, 0, stream>>>(
        x, wscale, ascale, bias, qscale, gindex, out, n_rows);
}